// Round 13
// baseline (265.234 us; speedup 1.0000x reference)
//
#include <hip/hip_runtime.h>
#include <hip/hip_bf16.h>
#include <math.h>

#define NUM_H 8
#define DK    64
#define DM    512
#define SEQ   2048
#define NB    2
#define MROWS (NB*SEQ)   // 4096

typedef unsigned short u16;
typedef unsigned int   u32;
typedef __attribute__((ext_vector_type(8))) __bf16 bf16x8;
typedef __attribute__((ext_vector_type(4))) float  f32x4;

__device__ __forceinline__ u16 f2bf(float v) {
    union { float f; u32 i; } x; x.f = v;
    u32 r = (x.i + 0x7FFFu + ((x.i >> 16) & 1u)) >> 16;
    return (u16)r;
}
__device__ __forceinline__ u16 f2h(float v) {
    union { _Float16 h; u16 u; } x; x.h = (_Float16)v; return x.u;
}
__device__ __forceinline__ float h2f(u16 u) {
    union { u16 u; _Float16 h; } x; x.u = u; return (float)x.h;
}
__device__ __forceinline__ bf16x8 ld_bf8(const u16* p) {
    union { uint4 u; bf16x8 v; } t;
    t.u = *(const uint4*)p;
    return t.v;
}
__device__ __forceinline__ uint4 pack8bf(const float* f) {
    uint4 o;
    o.x = (u32)f2bf(f[0]) | ((u32)f2bf(f[1]) << 16);
    o.y = (u32)f2bf(f[2]) | ((u32)f2bf(f[3]) << 16);
    o.z = (u32)f2bf(f[4]) | ((u32)f2bf(f[5]) << 16);
    o.w = (u32)f2bf(f[6]) | ((u32)f2bf(f[7]) << 16);
    return o;
}

// ---------------- MFMA GEMM core: OUT = X @ W^T + bias (W fp32, packed in-stage) ---
// BM=64, BN=64, BK=64. 256 thr / 4 waves (2x2, 32x32 out each). LDS stride 72 u16.
// Single-buffer 2-barrier K-loop (r9/r11/r12-proven; explicit pipelining regresses, r10).
#define MODE_QK 0
#define MODE_VT 1
#define MODE_FIN 2

template<int MODE, bool INBF>
__device__ __forceinline__ void gemm_core(
    const void* __restrict__ Xv, const float* __restrict__ W,
    const float* __restrict__ bias, void* __restrict__ outv,
    u16* As, u16* Bs, int row0, int col0)
{
    const int tid = threadIdx.x;
    const int lane = tid & 63, w = tid >> 6;
    const int ln15 = lane & 15, quad = lane >> 4;
    const int wm = (w >> 1) * 32, wn = (w & 1) * 32;

    f32x4 acc[2][2];
#pragma unroll
    for (int mt = 0; mt < 2; ++mt)
#pragma unroll
        for (int nt = 0; nt < 2; ++nt) acc[mt][nt] = (f32x4){0.f, 0.f, 0.f, 0.f};

    for (int kt = 0; kt < DM; kt += 64) {
        __syncthreads();
        // stage A: 64x64
#pragma unroll
        for (int g = 0; g < 2; ++g) {
            int idx = g * 2048 + tid * 8;
            int r = idx >> 6, c = idx & 63;
            if (INBF) {
                *(uint4*)&As[r * 72 + c] =
                    *(const uint4*)((const u16*)Xv + (size_t)(row0 + r) * DM + kt + c);
            } else {
                const float* xp = (const float*)Xv + (size_t)(row0 + r) * DM + kt + c;
                float4 a = *(const float4*)xp;
                float4 b2 = *(const float4*)(xp + 4);
                float f[8] = {a.x, a.y, a.z, a.w, b2.x, b2.y, b2.z, b2.w};
                *(uint4*)&As[r * 72 + c] = pack8bf(f);
            }
        }
        // stage B: 64x64, W fp32 layout [n][k] -> bf16 pack (L2-resident re-reads)
#pragma unroll
        for (int g = 0; g < 2; ++g) {
            int idx = g * 2048 + tid * 8;
            int r = idx >> 6, c = idx & 63;
            const float* wp = W + (size_t)(col0 + r) * DM + kt + c;
            float4 a = *(const float4*)wp;
            float4 b2 = *(const float4*)(wp + 4);
            float f[8] = {a.x, a.y, a.z, a.w, b2.x, b2.y, b2.z, b2.w};
            *(uint4*)&Bs[r * 72 + c] = pack8bf(f);
        }
        __syncthreads();

#pragma unroll
        for (int ks = 0; ks < 2; ++ks) {
            bf16x8 af[2], bfr[2];
#pragma unroll
            for (int mt = 0; mt < 2; ++mt)
                af[mt] = ld_bf8(&As[(wm + mt * 16 + ln15) * 72 + ks * 32 + quad * 8]);
#pragma unroll
            for (int nt = 0; nt < 2; ++nt)
                bfr[nt] = ld_bf8(&Bs[(wn + nt * 16 + ln15) * 72 + ks * 32 + quad * 8]);
#pragma unroll
            for (int mt = 0; mt < 2; ++mt)
#pragma unroll
                for (int nt = 0; nt < 2; ++nt)
                    acc[mt][nt] = __builtin_amdgcn_mfma_f32_16x16x32_bf16(
                        af[mt], bfr[nt], acc[mt][nt], 0, 0, 0);
        }
    }

    float bc[2];
#pragma unroll
    for (int nt = 0; nt < 2; ++nt) bc[nt] = bias[col0 + wn + nt * 16 + ln15];
    const int h = col0 >> 6;   // BN=64 == one head

    if (MODE == MODE_FIN) {
        float* outF = (float*)outv;
#pragma unroll
        for (int mt = 0; mt < 2; ++mt)
#pragma unroll
            for (int r = 0; r < 4; ++r) {
                int m = row0 + wm + mt * 16 + quad * 4 + r;
#pragma unroll
                for (int nt = 0; nt < 2; ++nt)
                    outF[(size_t)m * DM + col0 + wn + nt * 16 + ln15] = acc[mt][nt][r] + bc[nt];
            }
    } else if (MODE == MODE_QK) {
        u16* outB = (u16*)outv;
#pragma unroll
        for (int mt = 0; mt < 2; ++mt)
#pragma unroll
            for (int r = 0; r < 4; ++r) {
                int m = row0 + wm + mt * 16 + quad * 4 + r;
                int b = m >> 11, s2 = m & (SEQ - 1);
#pragma unroll
                for (int nt = 0; nt < 2; ++nt) {
                    int dk = wn + nt * 16 + ln15;
                    outB[((size_t)((b * NUM_H + h) * SEQ + s2)) * DK + dk] =
                        f2bf(acc[mt][nt][r] + bc[nt]);
                }
            }
    } else {   // MODE_VT: out [b][h][dk][s]; LDS transpose (reuse As, 64x72)
        u16* outB = (u16*)outv;
        __syncthreads();   // all frag reads done before As reuse
#pragma unroll
        for (int mt = 0; mt < 2; ++mt)
#pragma unroll
            for (int nt = 0; nt < 2; ++nt) {
                int dk = wn + nt * 16 + ln15;
#pragma unroll
                for (int r = 0; r < 4; ++r) {
                    int sl = wm + mt * 16 + quad * 4 + r;
                    As[dk * 72 + sl] = f2bf(acc[mt][nt][r] + bc[nt]);
                }
            }
        __syncthreads();
        int dk = tid >> 2, ch = (tid & 3) * 16;
        int b = row0 >> 11, s0 = row0 & (SEQ - 1);
        size_t base = ((size_t)((b * NUM_H + h) * DK + dk)) * SEQ + s0 + ch;
        *(uint4*)&outB[base]     = *(const uint4*)&As[dk * 72 + ch];
        *(uint4*)&outB[base + 8] = *(const uint4*)&As[dk * 72 + ch + 8];
    }
}

// Fused QKV: grid (64, 8, 3). Inputs and weights fp32. Block (0,0,0) zeroes the
// attn ticket/signal region in d_out (stream-ordered before attn; re-done every launch).
__global__ __launch_bounds__(256) void qkv_mfma(
    const float* __restrict__ xq, const float* __restrict__ xk, const float* __restrict__ xv,
    const float* __restrict__ Wq, const float* __restrict__ Wk, const float* __restrict__ Wv,
    const float* __restrict__ b0, const float* __restrict__ b1, const float* __restrict__ b2,
    u16* __restrict__ oQ, u16* __restrict__ oK, u16* __restrict__ oVt,
    u32* __restrict__ zeroReg)
{
    __shared__ u16 As[64 * 72];
    __shared__ u16 Bs[64 * 72];
    if (blockIdx.x == 0 && blockIdx.y == 0 && blockIdx.z == 0) {
#pragma unroll
        for (int j = 0; j < 4; ++j) zeroReg[j * 256 + threadIdx.x] = 0u;
    }
    const int row0 = blockIdx.x * 64, col0 = blockIdx.y * 64;
    const int z = blockIdx.z;
    const float* W = (z == 0) ? Wq : (z == 1) ? Wk : Wv;
    if (z == 2)
        gemm_core<MODE_VT, false>(xv, W, b2, oVt, As, Bs, row0, col0);
    else if (z == 0)
        gemm_core<MODE_QK, false>(xq, W, b0, oQ, As, Bs, row0, col0);
    else
        gemm_core<MODE_QK, false>(xk, W, b1, oK, As, Bs, row0, col0);
}

__global__ __launch_bounds__(256) void final_mfma(
    const u16* __restrict__ X, const float* __restrict__ W,
    const float* __restrict__ bias, float* __restrict__ out)
{
    __shared__ u16 As[64 * 72];
    __shared__ u16 Bs[64 * 72];
    gemm_core<MODE_FIN, true>(X, W, bias, out, As, Bs,
                              blockIdx.x * 64, blockIdx.y * 64);
}

// ---------------- MFMA flash attention, split-K2 + fused last-writer combine ----
// grid (32 qb, 16 bh, 2 z). Core loop identical to r9/r11/r12 (proven).
// Softmax exp(s-4) exact (scores ~N(0,1), |s|max≈6).
// Pair (qb,bh): first finisher writes partial O (fp16 x1/64, coalesced) + l to
// d_out scratch, fences, signals; second finisher combines with its registers
// and writes final C (bf16 row-major) into ws. Tickets zeroed by qkv.
#define LSTR 72
__global__ __launch_bounds__(256) void attn_mfma(
    const u16* __restrict__ Qg, const u16* __restrict__ Kg,
    const u16* __restrict__ Vtg, u16* __restrict__ Slt, float* __restrict__ Cl,
    u32* __restrict__ cnt, u16* __restrict__ Cc)
{
    __shared__ u16 Klds[64 * LSTR];
    __shared__ u16 Vtlds[64 * LSTR];
    __shared__ u16 Pls[64 * LSTR];

    const int tid = threadIdx.x;
    const int lane = tid & 63;
    const int w = tid >> 6;
    const int ln15 = lane & 15;
    const int quad = lane >> 4;
    const int bh = blockIdx.y;
    const int b = bh >> 3, h = bh & 7;
    const int qb = blockIdx.x * 64;
    const int z = blockIdx.z;
    const int k0 = z * (SEQ / 2), k1 = k0 + SEQ / 2;

    const u16* Qp = Qg + (size_t)bh * SEQ * DK;
    const u16* Kp = Kg + (size_t)bh * SEQ * DK;
    const u16* Vp = Vtg + (size_t)bh * DK * SEQ;   // [d][s]

    const int qrowA = qb + w * 16 + ln15;
    const bf16x8 qa0 = ld_bf8(&Qp[(size_t)qrowA * DK + quad * 8]);
    const bf16x8 qa1 = ld_bf8(&Qp[(size_t)qrowA * DK + 32 + quad * 8]);

    f32x4 O[4];
    float l_i[4] = {0.f, 0.f, 0.f, 0.f};
#pragma unroll
    for (int nt = 0; nt < 4; ++nt) O[nt] = (f32x4){0.f, 0.f, 0.f, 0.f};

    const int sr = tid >> 3;
    const int scl = (tid & 7) * 8;

    for (int kt = k0; kt < k1; kt += 64) {
        __syncthreads();
        *(uint4*)&Klds[sr * LSTR + scl]         = *(const uint4*)&Kp[(size_t)(kt + sr) * DK + scl];
        *(uint4*)&Klds[(sr + 32) * LSTR + scl]  = *(const uint4*)&Kp[(size_t)(kt + sr + 32) * DK + scl];
        *(uint4*)&Vtlds[sr * LSTR + scl]        = *(const uint4*)&Vp[(size_t)sr * SEQ + kt + scl];
        *(uint4*)&Vtlds[(sr + 32) * LSTR + scl] = *(const uint4*)&Vp[(size_t)(sr + 32) * SEQ + kt + scl];
        __syncthreads();

        const bool diagt = (kt == qb);
        // QK^T + exp + stage P
#pragma unroll
        for (int nt2 = 0; nt2 < 4; ++nt2) {
            bf16x8 kb0 = ld_bf8(&Klds[(nt2 * 16 + ln15) * LSTR + quad * 8]);
            bf16x8 kb1 = ld_bf8(&Klds[(nt2 * 16 + ln15) * LSTR + 32 + quad * 8]);
            f32x4 zacc = (f32x4){0.f, 0.f, 0.f, 0.f};
            zacc = __builtin_amdgcn_mfma_f32_16x16x32_bf16(qa0, kb0, zacc, 0, 0, 0);
            zacc = __builtin_amdgcn_mfma_f32_16x16x32_bf16(qa1, kb1, zacc, 0, 0, 0);
#pragma unroll
            for (int r = 0; r < 4; ++r) {
                float e = __expf(fmaf(zacc[r], 0.125f, -4.0f));
                if (diagt && (nt2 * 16 + ln15 == w * 16 + quad * 4 + r)) e = 0.f;
                l_i[r] += e;
                Pls[(w * 16 + quad * 4 + r) * LSTR + nt2 * 16 + ln15] = f2bf(e);
            }
        }

        // PV (same-wave P rows; in-wave LDS ordering — r6-r12-verified)
        bf16x8 pa0 = ld_bf8(&Pls[(w * 16 + ln15) * LSTR + quad * 8]);
        bf16x8 pa1 = ld_bf8(&Pls[(w * 16 + ln15) * LSTR + 32 + quad * 8]);
#pragma unroll
        for (int nt = 0; nt < 4; ++nt) {
            bf16x8 vb0 = ld_bf8(&Vtlds[(nt * 16 + ln15) * LSTR + quad * 8]);
            bf16x8 vb1 = ld_bf8(&Vtlds[(nt * 16 + ln15) * LSTR + 32 + quad * 8]);
            O[nt] = __builtin_amdgcn_mfma_f32_16x16x32_bf16(pa0, vb0, O[nt], 0, 0, 0);
            O[nt] = __builtin_amdgcn_mfma_f32_16x16x32_bf16(pa1, vb1, O[nt], 0, 0, 0);
        }
    }

    // reduce partial l across the 16-lane quad group
#pragma unroll
    for (int r = 0; r < 4; ++r) {
        float s = l_i[r];
        s += __shfl_xor(s, 1);
        s += __shfl_xor(s, 2);
        s += __shfl_xor(s, 4);
        s += __shfl_xor(s, 8);
        l_i[r] = s;
    }

    // ---- last-writer combine ----
    const int pair = bh * 32 + blockIdx.x;       // 512 pairs
    u32* sig = cnt + 512;
    u16* slot = Slt + (size_t)pair * 4096;       // 8 KB fp16 per pair
    __shared__ int role;
    if (tid == 0) role = (int)atomicAdd(&cnt[pair], 1u);
    __syncthreads();

    if (role == 0) {
        // early: write unnormalized partial O (x1/64) + l, release, signal
#pragma unroll
        for (int nt = 0; nt < 4; ++nt) {
            u32 lo = (u32)f2h(O[nt][0] * 0.015625f) | ((u32)f2h(O[nt][1] * 0.015625f) << 16);
            u32 hi = (u32)f2h(O[nt][2] * 0.015625f) | ((u32)f2h(O[nt][3] * 0.015625f) << 16);
            *(uint2*)&slot[tid * 16 + nt * 4] = make_uint2(lo, hi);
        }
        if (ln15 == 0) {
#pragma unroll
            for (int r = 0; r < 4; ++r)
                Cl[pair * 64 + w * 16 + quad * 4 + r] = l_i[r];
        }
        __threadfence();
        __syncthreads();
        if (tid == 0) atomicAdd(&sig[pair], 1u);
    } else {
        // late: acquire early's partial, combine with own registers, write C
        if (tid == 0) {
            while (atomicAdd(&sig[pair], 0u) == 0u) __builtin_amdgcn_s_sleep(8);
        }
        __syncthreads();
        __threadfence();
        float oth[4][4];
#pragma unroll
        for (int nt = 0; nt < 4; ++nt) {
            uint2 v = *(const uint2*)&slot[tid * 16 + nt * 4];
            oth[nt][0] = h2f((u16)(v.x & 0xffff));
            oth[nt][1] = h2f((u16)(v.x >> 16));
            oth[nt][2] = h2f((u16)(v.y & 0xffff));
            oth[nt][3] = h2f((u16)(v.y >> 16));
        }
#pragma unroll
        for (int r = 0; r < 4; ++r) {
            float lo2 = Cl[pair * 64 + w * 16 + quad * 4 + r];
            float inv = 1.f / (l_i[r] + lo2);
            int s = qb + w * 16 + quad * 4 + r;
            size_t base = ((size_t)(b * SEQ + s)) * DM + h * DK;
#pragma unroll
            for (int nt = 0; nt < 4; ++nt)
                Cc[base + nt * 16 + ln15] = f2bf((O[nt][r] + 64.f * oth[nt][r]) * inv);
        }
    }
}

extern "C" void kernel_launch(void* const* d_in, const int* in_sizes, int n_in,
                              void* d_out, int out_size, void* d_ws, size_t ws_size,
                              hipStream_t stream) {
    const float* q  = (const float*)d_in[0];
    const float* k  = (const float*)d_in[1];
    const float* v  = (const float*)d_in[2];
    const float* Wq = (const float*)d_in[3];
    const float* bq = (const float*)d_in[4];
    const float* Wk = (const float*)d_in[5];
    const float* bk = (const float*)d_in[6];
    const float* Wv = (const float*)d_in[7];
    const float* bv = (const float*)d_in[8];
    const float* Wo = (const float*)d_in[9];
    const float* bo = (const float*)d_in[10];
    float* out = (float*)d_out;

    // ws (16 MB): Qb, Kb, Vtb (bf16 4 MB each) + Cc (final C, bf16 row-major, 4 MB).
    const size_t TSZ = (size_t)MROWS * DM;   // 2,097,152
    u16* Qb  = (u16*)d_ws;
    u16* Kb  = Qb + TSZ;
    u16* Vtb = Qb + 2 * TSZ;
    u16* Cc  = Qb + 3 * TSZ;

    // d_out scratch during attn (all dead before final overwrites d_out):
    //   [0 .. 4 MB)        512 partial-O slots (8 KB fp16 each)
    //   [4 MB .. +128 KB)  partial l (fp32 [512][64])
    //   then 4 KB          tickets[512] + signals[512] (zeroed by qkv each launch)
    u16*   Slt = (u16*)d_out;
    float* Cl  = (float*)(Slt + 2097152);
    u32*   cnt = (u32*)(Cl + 32768);

    dim3 blk(256);
    dim3 gq(MROWS / 64, DM / 64, 3);         // (64, 8, 3) = 1536 blocks, 6/CU
    hipLaunchKernelGGL(qkv_mfma, gq, blk, 0, stream,
                       q, k, v, Wq, Wk, Wv, bq, bk, bv, Qb, Kb, Vtb, cnt);
    dim3 ga(SEQ / 64, NB * NUM_H, 2);        // (32, 16, 2) split-K + fused combine
    hipLaunchKernelGGL(attn_mfma, ga, blk, 0, stream, Qb, Kb, Vtb, Slt, Cl, cnt, Cc);
    dim3 gf(MROWS / 64, DM / 64);            // (64, 8)
    hipLaunchKernelGGL(final_mfma, gf, blk, 0, stream, Cc, Wo, bo, out);
}